// Round 13
// baseline (28131.763 us; speedup 1.0000x reference)
//
#include <hip/hip_runtime.h>
#include <hip/hip_bf16.h>

// Problem constants
#define Tt   800
#define Uu   64
#define Cc   80
#define NBLK 128
#define ASTR 648     // LDS A row stride (shorts)
#define ALIMB 10368  // 16*ASTR

// hbuf: [16 chunk][2 buf][2 limb][8 row][512] shorts
#define HBC 16384    // shorts per chunk

#define OUT_PHI 52428800u
#define OUT_W   58982400u

// ws byte offsets
#define WS_HBUF 0u          // 16*16384*2 = 524,288
#define WS_SEQ  524288u     // 16 chunks * 32 ints = 2,048
#define WS_NEED 526336u
#define POLL_CAP 200000

typedef __attribute__((ext_vector_type(4))) int   i32x4;
typedef __attribute__((ext_vector_type(8))) short short8;
typedef __attribute__((ext_vector_type(4))) float f32x4;
typedef unsigned long long u64;

__device__ __forceinline__ float b2f(unsigned short u){ unsigned int i = ((unsigned int)u)<<16; float f; __builtin_memcpy(&f,&i,4); return f; }
__device__ __forceinline__ unsigned short f2b(float f){ __hip_bfloat16 h = __float2bfloat16(f); unsigned short u; __builtin_memcpy(&u,&h,2); return u; }
__device__ __forceinline__ float sigm(float v){ return 1.f/(1.f + __expf(-v)); }
__device__ __forceinline__ float tanh_(float v){ return 1.f - 2.f/(1.f + __expf(2.f*v)); }

__device__ __forceinline__ void drain_vm(){ asm volatile("s_waitcnt vmcnt(0)" ::: "memory"); }
#define WAIT_VM(N) asm volatile("s_waitcnt vmcnt(" #N ")" ::: "memory")

// MALL-coherent (sc0 sc1) — the ONLY proven cross-CU mechanism (R6/R8/R10/R11)
__device__ __forceinline__ void gld16(i32x4* dst, const void* addr) {
  asm volatile("global_load_dwordx4 %0, %1, off sc0 sc1" : "=v"(*dst) : "v"(addr));
}
__device__ __forceinline__ void gst16(void* addr, i32x4 v) {
  asm volatile("global_store_dwordx4 %0, %1, off sc0 sc1" :: "v"(addr), "v"(v) : "memory");
}
__device__ __forceinline__ int gld4(const int* p) {
  int v;
  asm volatile("global_load_dword %0, %1, off sc0 sc1" : "=v"(v) : "v"(p));
  asm volatile("s_waitcnt vmcnt(0)" ::: "memory");
  return v;
}
__device__ __forceinline__ void gst4(int* p, int v) {
  asm volatile("global_store_dword %0, %1, off sc0 sc1" :: "v"(p), "v"(v) : "memory");
}

// ---- prep: zero hbuf + seq ----
__global__ void prep(unsigned short* __restrict__ hbuf, int* __restrict__ seq) {
  int i = blockIdx.x*256 + threadIdx.x;
  if (i < 262144) hbuf[i] = 0;
  else if (i < 262656) seq[i - 262144] = 0;
}

__global__ __launch_bounds__(512, 1) void rnn_main(
    const float* __restrict__ x,      // [128][800][3]
    const float* __restrict__ sent,   // [128][64][80]
    const int*   __restrict__ slen,   // [128]
    const float* __restrict__ bias,   // [2048]
    const float* __restrict__ bwin,   // [30]
    const float* __restrict__ Wwin,   // [512][30]
    const float* __restrict__ Wx,     // [83][2048]
    const float* __restrict__ Wh,     // [512][2048]
    unsigned short* __restrict__ hbuf,
    int* __restrict__ seq,
    float* __restrict__ out)
{
  __shared__ __align__(16) unsigned short lA[2*ALIMB];    // 41,472 B (rows 8-15 stay zero)
  __shared__ __align__(16) unsigned short lWwF[32768];    // 65,536 B
  __shared__ __align__(16) float lPart[16*64*4];          // 16,384 B
  __shared__ float lWin[8*32];
  __shared__ float lE[8*32];
  __shared__ float lKap[2*8*16];                          // per-chunk kappa
  __shared__ float lPhi[8*64];
  __shared__ __align__(16) unsigned short lHout[2*8*32];  // 1,024 B
  __shared__ float lBwin[32];
  __shared__ int   lLen[16];

  const int jj   = blockIdx.x & 15;   // z-column slice
  const int rho  = blockIdx.x >> 4;   // replica: serves chunks 2rho, 2rho+1
  const int tid  = threadIdx.x;
  const int wave = tid >> 6;
  const int lane = tid & 63;
  const int l15  = lane & 15, lhi = lane >> 4;

  // ---- one-time LDS fills ----
  for (int i = tid; i < 2*ALIMB/4; i += 512) ((u64*)lA)[i] = 0;
  for (int e = tid; e < 16384; e += 512) {     // Wwin MFMA frags hi/lo
    int j = e & 7, ln = (e >> 3) & 63, nt = (e >> 9) & 1, kt = e >> 10;
    int k   = kt*32 + (ln >> 4)*8 + j;
    int col = nt*16 + (ln & 15);
    float v = (col < 30) ? Wwin[k*30 + col] : 0.f;
    unsigned short hi = f2b(v);
    lWwF[e]         = hi;
    lWwF[16384 + e] = f2b(v - b2f(hi));
  }
  if (tid < 32)  lBwin[tid] = (tid < 30) ? bwin[tid] : 0.f;
  if (tid < 16)  lLen[tid]  = slen[rho*16 + tid];
  for (int i = tid; i < 256; i += 512) lKap[i] = 0.f;

  // ---- persistent weight fragments in REGISTERS ((512,1) -> 256 VGPR budget) ----
  short8 bfh[20], bfl[20];
  const int zc = (l15 >> 2)*512 + jj*32 + wave*4 + (l15 & 3);   // gate*512 + unit
  #pragma unroll
  for (int kt = 0; kt < 20; ++kt) {
    short8 hv, lv;
    #pragma unroll
    for (int j = 0; j < 8; ++j) {
      int k = kt*32 + lhi*8 + j;
      float v;
      if (k < 512)      v = Wh[(size_t)k*2048 + zc];
      else if (k < 515) v = Wx[(size_t)(k-512)*2048 + zc];
      else if (k < 544) v = 0.f;
      else if (k < 624) v = Wx[(size_t)(3 + (k-544))*2048 + zc];
      else              v = 0.f;
      unsigned short hh = f2b(v);
      hv[j] = (short)hh;
      lv[j] = (short)f2b(v - b2f(hh));
    }
    bfh[kt] = hv;
    bfl[kt] = lv;
  }
  #pragma unroll
  for (int kt = 0; kt < 20; ++kt) {   // keep live in VGPRs
    asm volatile("" : "+v"(bfh[kt]));
    asm volatile("" : "+v"(bfl[kt]));
  }
  const float bias_r = bias[zc];
  __syncthreads();

  float c_reg[2][4] = {{0.f,0.f,0.f,0.f},{0.f,0.f,0.f,0.f}};

  // ---- win/phi/w for chunk ci (8 rows), output step tt; all 16 slice-blocks redundant ----
  auto phaseW = [&](int ci, int cg, int tt, bool writeState) {
    {
      f32x4 aw0 = {0.f,0.f,0.f,0.f}, aw1 = {0.f,0.f,0.f,0.f};
      #pragma unroll
      for (int kk = 0; kk < 2; ++kk) {
        const int kt = wave*2 + kk;
        short8 ah = *(const short8*)&lA[l15*ASTR + kt*32 + lhi*8];
        short8 al = *(const short8*)&lA[ALIMB + l15*ASTR + kt*32 + lhi*8];
        short8 bh0 = *(const short8*)&lWwF[((kt*2+0)*64 + lane)*8];
        short8 bl0 = *(const short8*)&lWwF[16384 + ((kt*2+0)*64 + lane)*8];
        short8 bh1 = *(const short8*)&lWwF[((kt*2+1)*64 + lane)*8];
        short8 bl1 = *(const short8*)&lWwF[16384 + ((kt*2+1)*64 + lane)*8];
        aw0 = __builtin_amdgcn_mfma_f32_16x16x32_bf16(ah, bh0, aw0, 0,0,0);
        aw0 = __builtin_amdgcn_mfma_f32_16x16x32_bf16(ah, bl0, aw0, 0,0,0);
        aw0 = __builtin_amdgcn_mfma_f32_16x16x32_bf16(al, bh0, aw0, 0,0,0);
        aw0 = __builtin_amdgcn_mfma_f32_16x16x32_bf16(al, bl0, aw0, 0,0,0);
        aw1 = __builtin_amdgcn_mfma_f32_16x16x32_bf16(ah, bh1, aw1, 0,0,0);
        aw1 = __builtin_amdgcn_mfma_f32_16x16x32_bf16(ah, bl1, aw1, 0,0,0);
        aw1 = __builtin_amdgcn_mfma_f32_16x16x32_bf16(al, bh1, aw1, 0,0,0);
        aw1 = __builtin_amdgcn_mfma_f32_16x16x32_bf16(al, bl1, aw1, 0,0,0);
      }
      *(f32x4*)&lPart[((wave*2+0)*64 + lane)*4] = aw0;
      *(f32x4*)&lPart[((wave*2+1)*64 + lane)*4] = aw1;
    }
    __syncthreads();
    if (tid < 256) {           // reduce: nt(2) x row(8) x col(16)
      const int nt = tid >> 7, row = (tid >> 4) & 7, col = tid & 15;
      const int ln = ((row >> 2) << 4) | col, reg = row & 3;
      float s = 0.f;
      #pragma unroll
      for (int w = 0; w < 8; ++w) s += lPart[((w*2 + nt)*64 + ln)*4 + reg];
      lWin[row*32 + nt*16 + col] = s + lBwin[nt*16 + col];
    }
    __syncthreads();
    if (tid < 256) {
      const int r = tid >> 5, j = tid & 31;
      if (j < 30) lE[r*32 + j] = __expf(lWin[r*32 + j]);
    }
    __syncthreads();
    if (tid < 80) {            // kappa += exp(k_hat); phi uses updated kappa
      const int r = tid / 10, k = tid % 10;
      lKap[ci*128 + r*16 + k] += lE[r*32 + 20 + k];
    }
    __syncthreads();
    {                          // phi: 8 rows x 64 u = 512 threads exactly
      const int r = tid >> 6, u = tid & 63;
      const float u1 = (float)u + 1.f;
      float phi = 0.f;
      #pragma unroll
      for (int k = 0; k < 10; ++k) {
        float d = lKap[ci*128 + r*16 + k] - u1;
        phi += lE[r*32 + k] * __expf(-lE[r*32 + 10 + k] * d * d);
      }
      if (u >= lLen[ci*8 + r]) phi = 0.f;
      lPhi[r*64 + u] = phi;
      if (jj == r) out[OUT_PHI + ((size_t)(cg*8 + r)*Tt + tt)*Uu + u] = phi;
    }
    __syncthreads();
    #pragma unroll
    for (int it2 = 0; it2 < 2; ++it2) {   // w: 8 rows x 80 c = 640
      const int pair = tid + it2*512;
      if (pair < 640) {
        const int r = pair / 80, c = pair % 80;
        const float* sp = sent + (size_t)(cg*8 + r)*(Uu*Cc) + c;
        float s = 0.f;
        #pragma unroll 8
        for (int u = 0; u < Uu; ++u) s += lPhi[r*64 + u] * sp[u*Cc];
        if (jj == r) out[OUT_W + ((size_t)(cg*8 + r)*Tt + tt)*Cc + c] = s;
        if (writeState) {
          unsigned short hi = f2b(s);
          lA[r*ASTR + 544 + c]         = hi;
          lA[ALIMB + r*ASTR + 544 + c] = f2b(s - b2f(hi));
        }
      }
    }
    __syncthreads();
  };

  // ---- one pipelined chunk-step ----
  auto stepChunk = [&](int ci, int t) {
    const int cg = rho*2 + ci;
    unsigned short* hbG = hbuf + cg*HBC;
    int* seqG = seq + cg*32;

    if (t > 0) {
      if (wave == 0) {           // poll one 64B seq line (16 producers)
        const int* sp = seqG + (lane & 15);
        int it = 0;
        for (;;) {
          int v = gld4(sp);
          if (__all(v >= t)) break;
          if (++it > POLL_CAP) break;
          __builtin_amdgcn_s_sleep(1);
        }
      }
      __syncthreads();
      {  // stage h_{t-1}: 8 rows x 512 x 2 limbs
        const unsigned short* hb = hbG + (t&1)*8192;
        const int row = tid >> 6;
        i32x4 vh, vl;
        gld16(&vh, hb + row*512 + lane*8);
        gld16(&vl, hb + 4096 + row*512 + lane*8);
        WAIT_VM(0);
        __builtin_amdgcn_sched_barrier(0);
        *(i32x4*)&lA[row*ASTR + lane*8]         = vh;
        *(i32x4*)&lA[ALIMB + row*ASTR + lane*8] = vl;
      }
    }
    if (tid < 24) {   // x_t -> k 512..514
      const int row = tid / 3, comp = tid % 3;
      float xv = x[((size_t)(cg*8 + row)*Tt + t)*3 + comp];
      unsigned short hh = f2b(xv);
      lA[row*ASTR + 512 + comp]         = hh;
      lA[ALIMB + row*ASTR + 512 + comp] = f2b(xv - b2f(hh));
    }
    __syncthreads();

    if (t > 0) phaseW(ci, cg, t-1, true);   // fills lA w-region

    // z = A @ Wc (20 kt, hi/lo); rows 8-15 of A are zero
    f32x4 acc0 = {0.f,0.f,0.f,0.f}, acc1 = {0.f,0.f,0.f,0.f};
    const int arow = l15*ASTR + lhi*8;
    #pragma unroll
    for (int kt = 0; kt < 20; ++kt) {
      short8 ah = *(const short8*)&lA[arow + kt*32];
      short8 al = *(const short8*)&lA[ALIMB + arow + kt*32];
      acc0 = __builtin_amdgcn_mfma_f32_16x16x32_bf16(ah, bfh[kt], acc0, 0,0,0);
      acc1 = __builtin_amdgcn_mfma_f32_16x16x32_bf16(ah, bfl[kt], acc1, 0,0,0);
      acc1 = __builtin_amdgcn_mfma_f32_16x16x32_bf16(al, bfh[kt], acc1, 0,0,0);
    }

    // gates -> h_t (rows 0..7 real)
    #pragma unroll
    for (int r = 0; r < 4; ++r) {
      float v   = acc0[r] + acc1[r] + bias_r;
      float t4  = __shfl_xor(v, 4);
      float t8  = __shfl_xor(v, 8);
      float t12 = __shfl_xor(v, 12);
      float ig = sigm(v), fg = sigm(t4), gg = tanh_(t8), og = sigm(t12);
      float cn = fg*c_reg[ci][r] + ig*gg;
      c_reg[ci][r] = cn;
      float h = og*tanh_(cn);
      const int rr = lhi*4 + r;
      if (l15 < 4 && rr < 8) {
        const int ui = wave*4 + l15;
        unsigned short h16 = f2b(h);
        lHout[rr*32 + ui]       = h16;
        lHout[256 + rr*32 + ui] = f2b(h - b2f(h16));
        out[((size_t)(cg*8 + rr)*Tt + t)*512 + jj*32 + ui] = h;
      }
    }
    __syncthreads();

    // coalesced h stores: 8 rows x 2 limbs x 4 x 16B = 64 stores
    {
      unsigned short* hbn = hbG + ((t+1)&1)*8192;
      if (tid < 64) {
        const int rr = tid >> 3, limb = (tid >> 2) & 1, q = tid & 3;
        i32x4 v = *(const i32x4*)&lHout[limb*256 + rr*32 + q*8];
        gst16(hbn + limb*4096 + rr*512 + jj*32 + q*8, v);
        drain_vm();
      }
    }
    __syncthreads();
    if (tid == 0) gst4(seqG + jj, t+1);      // publish after all stores acked
  };

  for (int t = 0; t < Tt; ++t) {
    stepChunk(0, t);      // while A's exchange round-trips ...
    stepChunk(1, t);      // ... B computes (and vice versa)
  }

  // ---- epilogue: phi/w for t=799, both chunks ----
  #pragma unroll
  for (int ci = 0; ci < 2; ++ci) {
    const int cg = rho*2 + ci;
    unsigned short* hbG = hbuf + cg*HBC;
    int* seqG = seq + cg*32;
    if (wave == 0) {
      const int* sp = seqG + (lane & 15);
      int it = 0;
      for (;;) {
        int v = gld4(sp);
        if (__all(v >= Tt)) break;
        if (++it > POLL_CAP) break;
        __builtin_amdgcn_s_sleep(1);
      }
    }
    __syncthreads();
    {
      const unsigned short* hb = hbG + (Tt&1)*8192;   // h_799 in buf 0
      const int row = tid >> 6;
      i32x4 vh, vl;
      gld16(&vh, hb + row*512 + lane*8);
      gld16(&vl, hb + 4096 + row*512 + lane*8);
      WAIT_VM(0);
      __builtin_amdgcn_sched_barrier(0);
      *(i32x4*)&lA[row*ASTR + lane*8]         = vh;
      *(i32x4*)&lA[ALIMB + row*ASTR + lane*8] = vl;
    }
    __syncthreads();
    phaseW(ci, cg, Tt-1, false);
  }
}

extern "C" void kernel_launch(void* const* d_in, const int* in_sizes, int n_in,
                              void* d_out, int out_size, void* d_ws, size_t ws_size,
                              hipStream_t stream) {
  (void)in_sizes; (void)n_in; (void)out_size;
  if (ws_size < WS_NEED) return;
  const float* x    = (const float*)d_in[0];
  const float* sent = (const float*)d_in[1];
  const int*   sl   = (const int*)d_in[2];
  const float* Wx   = (const float*)d_in[3];
  const float* Wh   = (const float*)d_in[4];
  const float* bias = (const float*)d_in[5];
  const float* Wwin = (const float*)d_in[6];
  const float* bwin = (const float*)d_in[7];

  char* ws = (char*)d_ws;
  unsigned short* hbuf = (unsigned short*)(ws + WS_HBUF);
  int* seq = (int*)(ws + WS_SEQ);
  float* out = (float*)d_out;

  prep<<<1027, 256, 0, stream>>>(hbuf, seq);
  rnn_main<<<NBLK, 512, 0, stream>>>(x, sent, sl, bias, bwin, Wwin, Wx, Wh,
                                     hbuf, seq, out);
}

// Round 14
// 12713.439 us; speedup vs baseline: 2.2128x; 2.2128x over previous
//
#include <hip/hip_runtime.h>
#include <hip/hip_bf16.h>

// Problem constants
#define Tt   800
#define Uu   64
#define Cc   80
#define NBLK 128
#define ASTR 648     // LDS A row stride (shorts)
#define ALIMB 10368  // 16*ASTR

// hbuf: [8 grp][2 buf][2 limb][16 row][512] shorts
#define HB_G    32768
#define HB_BUF  16384
#define HB_LIMB 8192

#define OUT_PHI 52428800u
#define OUT_W   58982400u

// ws byte offsets
#define WS_HBUF  0u          // 524,288
#define WS_SEQ   524288u     // 8 groups x 16 ints = 512
#define WS_SENTT 524800u     // [128][80][64] f32 = 2,621,440
#define WS_NEED  3146240u
#define POLL_CAP 2000000

typedef __attribute__((ext_vector_type(4))) int   i32x4;
typedef __attribute__((ext_vector_type(8))) short short8;
typedef __attribute__((ext_vector_type(4))) float f32x4;
typedef unsigned long long u64;

__device__ __forceinline__ float b2f(unsigned short u){ unsigned int i = ((unsigned int)u)<<16; float f; __builtin_memcpy(&f,&i,4); return f; }
__device__ __forceinline__ unsigned short f2b(float f){ __hip_bfloat16 h = __float2bfloat16(f); unsigned short u; __builtin_memcpy(&u,&h,2); return u; }
__device__ __forceinline__ float sigm(float v){ return 1.f/(1.f + __expf(-v)); }
__device__ __forceinline__ float tanh_(float v){ return 1.f - 2.f/(1.f + __expf(2.f*v)); }

__device__ __forceinline__ void drain_vm(){ asm volatile("s_waitcnt vmcnt(0)" ::: "memory"); }
#define WAIT_VM(N) asm volatile("s_waitcnt vmcnt(" #N ")" ::: "memory")

// MALL-coherent (sc0 sc1) — the ONLY proven cross-CU mechanism (R6/R8/R10/R11/R13)
__device__ __forceinline__ void gld16(i32x4* dst, const void* addr) {
  asm volatile("global_load_dwordx4 %0, %1, off sc0 sc1" : "=v"(*dst) : "v"(addr));
}
__device__ __forceinline__ void gst16(void* addr, i32x4 v) {
  asm volatile("global_store_dwordx4 %0, %1, off sc0 sc1" :: "v"(addr), "v"(v) : "memory");
}
__device__ __forceinline__ int gld4(const int* p) {
  int v;
  asm volatile("global_load_dword %0, %1, off sc0 sc1" : "=v"(v) : "v"(p));
  asm volatile("s_waitcnt vmcnt(0)" ::: "memory");
  return v;
}
__device__ __forceinline__ void gst4(int* p, int v) {
  asm volatile("global_store_dword %0, %1, off sc0 sc1" :: "v"(p), "v"(v) : "memory");
}

// ---- prep: zero hbuf+seq; build sentT[r][c][u] = sent[r][u][c] ----
__global__ void prep(const float* __restrict__ sent,
                     unsigned short* __restrict__ hbuf, int* __restrict__ seq,
                     float* __restrict__ sentT) {
  int i = blockIdx.x*256 + threadIdx.x;
  if (i < 262144) hbuf[i] = 0;
  else if (i < 262272) seq[i - 262144] = 0;
  int j = i - 262272;
  if (j >= 0 && j < 655360) {
    int r = j / 5120, rem = j % 5120, c = rem >> 6, u = rem & 63;
    sentT[j] = sent[r*5120 + u*80 + c];
  }
}

__global__ __launch_bounds__(512, 1) void rnn_main(
    const float* __restrict__ x,      // [128][800][3]
    const int*   __restrict__ slen,   // [128]
    const float* __restrict__ bias,   // [2048]
    const float* __restrict__ bwin,   // [30]
    const float* __restrict__ Wwin,   // [512][30]
    const float* __restrict__ Wx,     // [83][2048]
    const float* __restrict__ Wh,     // [512][2048]
    unsigned short* __restrict__ hbuf,
    int* __restrict__ seq,
    const float* __restrict__ sentT,  // [128][80][64]
    float* __restrict__ out)
{
  __shared__ __align__(16) unsigned short lA[2*ALIMB];    // 41,472 B
  __shared__ __align__(16) unsigned short lWwF[32768];    // 65,536 B
  __shared__ __align__(16) float lPart[8*2*64*4];         // 16,384 B
  __shared__ float lWin[16*32];
  __shared__ float lE[16*32];
  __shared__ float lKap[16*16];
  __shared__ float lPhi[16*64];
  __shared__ __align__(16) unsigned short lHout[2*16*32];
  __shared__ float lBwin[32];
  __shared__ int   lLen[16];

  const int g    = blockIdx.x >> 4;
  const int jj   = blockIdx.x & 15;       // owned slice / owned row
  const int grow = g*16 + jj;
  const int tid  = threadIdx.x;
  const int wave = tid >> 6;
  const int lane = tid & 63;
  const int l15  = lane & 15, lhi = lane >> 4;

  int* seqG = seq + g*16;
  unsigned short* hbG = hbuf + g*HB_G;

  // ---- one-time LDS fills ----
  for (int i = tid; i < 2*ALIMB/4; i += 512) ((u64*)lA)[i] = 0;
  for (int e = tid; e < 16384; e += 512) {     // Wwin MFMA fragments, hi/lo
    int j = e & 7, ln = (e >> 3) & 63, nt = (e >> 9) & 1, kt = e >> 10;
    int k   = kt*32 + (ln >> 4)*8 + j;
    int col = nt*16 + (ln & 15);
    float v = (col < 30) ? Wwin[k*30 + col] : 0.f;
    unsigned short hi = f2b(v);
    lWwF[e]         = hi;
    lWwF[16384 + e] = f2b(v - b2f(hi));
  }
  if (tid < 32)  lBwin[tid] = (tid < 30) ? bwin[tid] : 0.f;
  if (tid < 16)  lLen[tid]  = slen[g*16 + tid];
  for (int i = tid; i < 256; i += 512) lKap[i] = 0.f;

  // ---- per-wave persistent weight fragments ----
  short8 bfh[20], bfl[20];
  const int zc = (l15 >> 2)*512 + jj*32 + wave*4 + (l15 & 3);   // gate*512 + unit
  #pragma unroll
  for (int kt = 0; kt < 20; ++kt) {
    short8 hv, lv;
    #pragma unroll
    for (int j = 0; j < 8; ++j) {
      int k = kt*32 + lhi*8 + j;
      float v;
      if (k < 512)      v = Wh[(size_t)k*2048 + zc];
      else if (k < 515) v = Wx[(size_t)(k-512)*2048 + zc];
      else if (k < 544) v = 0.f;
      else if (k < 624) v = Wx[(size_t)(3 + (k-544))*2048 + zc];
      else              v = 0.f;
      unsigned short hh = f2b(v);
      hv[j] = (short)hh;
      lv[j] = (short)f2b(v - b2f(hh));
    }
    bfh[kt] = hv;
    bfl[kt] = lv;
  }
  const float bias_r = bias[zc];
  __syncthreads();

  float c_reg[4] = {0.f,0.f,0.f,0.f};

  // ---- win/phi/w for output step tt (all blocks redundant over 16 rows) ----
  auto phaseW = [&](int tt, bool writeState) {
    {
      f32x4 aw0 = {0.f,0.f,0.f,0.f}, aw1 = {0.f,0.f,0.f,0.f};
      #pragma unroll
      for (int kk = 0; kk < 2; ++kk) {
        const int kt = wave*2 + kk;
        short8 ah = *(const short8*)&lA[l15*ASTR + kt*32 + lhi*8];
        short8 al = *(const short8*)&lA[ALIMB + l15*ASTR + kt*32 + lhi*8];
        short8 bh0 = *(const short8*)&lWwF[((kt*2+0)*64 + lane)*8];
        short8 bl0 = *(const short8*)&lWwF[16384 + ((kt*2+0)*64 + lane)*8];
        short8 bh1 = *(const short8*)&lWwF[((kt*2+1)*64 + lane)*8];
        short8 bl1 = *(const short8*)&lWwF[16384 + ((kt*2+1)*64 + lane)*8];
        aw0 = __builtin_amdgcn_mfma_f32_16x16x32_bf16(ah, bh0, aw0, 0,0,0);
        aw0 = __builtin_amdgcn_mfma_f32_16x16x32_bf16(ah, bl0, aw0, 0,0,0);
        aw0 = __builtin_amdgcn_mfma_f32_16x16x32_bf16(al, bh0, aw0, 0,0,0);
        aw1 = __builtin_amdgcn_mfma_f32_16x16x32_bf16(ah, bh1, aw1, 0,0,0);
        aw1 = __builtin_amdgcn_mfma_f32_16x16x32_bf16(ah, bl1, aw1, 0,0,0);
        aw1 = __builtin_amdgcn_mfma_f32_16x16x32_bf16(al, bh1, aw1, 0,0,0);
      }
      *(f32x4*)&lPart[((wave*2+0)*64 + lane)*4] = aw0;
      *(f32x4*)&lPart[((wave*2+1)*64 + lane)*4] = aw1;
    }
    __syncthreads();
    {
      const int nt = tid >> 8, row = (tid >> 4) & 15, col = tid & 15;
      const int ln = ((row >> 2) << 4) | col, reg = row & 3;
      float s = 0.f;
      #pragma unroll
      for (int w = 0; w < 8; ++w) s += lPart[((w*2 + nt)*64 + ln)*4 + reg];
      lWin[row*32 + nt*16 + col] = s + lBwin[nt*16 + col];
    }
    __syncthreads();
    {
      const int r = tid >> 5, j = tid & 31;
      if (j < 30) lE[r*32 + j] = __expf(lWin[r*32 + j]);
    }
    __syncthreads();
    if (tid < 160) {            // kappa += exp(k_hat); phi uses updated kappa
      const int r = tid / 10, k = tid % 10;
      lKap[r*16 + k] += lE[r*32 + 20 + k];
    }
    __syncthreads();
    #pragma unroll
    for (int it2 = 0; it2 < 2; ++it2) {   // phi: 16 rows x 64 u
      const int pair = tid + it2*512;
      const int r = pair >> 6, u = pair & 63;
      const float u1 = (float)u + 1.f;
      float phi = 0.f;
      #pragma unroll
      for (int k = 0; k < 10; ++k) {
        float d = lKap[r*16 + k] - u1;
        phi += lE[r*32 + k] * __expf(-lE[r*32 + 10 + k] * d * d);
      }
      if (u >= lLen[r]) phi = 0.f;
      lPhi[r*64 + u] = phi;
      if (r == jj) out[OUT_PHI + ((size_t)grow*Tt + tt)*Uu + u] = phi;
    }
    __syncthreads();
    for (int it2 = 0; it2 < 3; ++it2) {   // w: 16 rows x 80 c, sentT contiguous
      const int pair = tid + it2*512;
      if (pair < 1280) {
        const int r = pair / 80, c = pair % 80;
        const float* sp = sentT + ((size_t)(g*16 + r)*80 + c)*64;   // plain cached
        float s = 0.f;
        #pragma unroll 8
        for (int u = 0; u < Uu; ++u) s += lPhi[r*64 + u] * sp[u];
        if (r == jj) out[OUT_W + ((size_t)grow*Tt + tt)*Cc + c] = s;
        if (writeState) {
          unsigned short hi = f2b(s);
          lA[r*ASTR + 544 + c]         = hi;
          lA[ALIMB + r*ASTR + 544 + c] = f2b(s - b2f(hi));
        }
      }
    }
    __syncthreads();
  };

  for (int t = 0; t < Tt; ++t) {
    if (t > 0) {
      if (wave == 0) {        // poll one 64B seq line (16 producers)
        const int* sp = seqG + (lane & 15);
        int it = 0;
        for (;;) {
          int v = gld4(sp);
          if (__all(v >= t)) break;
          if (++it > POLL_CAP) break;
          __builtin_amdgcn_s_sleep(1);
        }
      }
      __syncthreads();
      // stage h_{t-1} (hi+lo, all 16 rows)
      const unsigned short* hb = hbG + (t&1)*HB_BUF;
      const int r0 = tid >> 6, q0 = lane;
      i32x4 va, vb, vc, vd;
      gld16(&va, hb + r0*512 + q0*8);
      gld16(&vb, hb + (r0+8)*512 + q0*8);
      gld16(&vc, hb + HB_LIMB + r0*512 + q0*8);
      gld16(&vd, hb + HB_LIMB + (r0+8)*512 + q0*8);
      WAIT_VM(0);
      __builtin_amdgcn_sched_barrier(0);
      *(i32x4*)&lA[r0*ASTR + q0*8]             = va;
      *(i32x4*)&lA[(r0+8)*ASTR + q0*8]         = vb;
      *(i32x4*)&lA[ALIMB + r0*ASTR + q0*8]     = vc;
      *(i32x4*)&lA[ALIMB + (r0+8)*ASTR + q0*8] = vd;
    }
    if (tid < 48) {   // x_t -> k 512..514
      const int row = tid / 3, comp = tid % 3;
      float xv = x[((size_t)(g*16 + row)*Tt + t)*3 + comp];
      unsigned short hh = f2b(xv);
      lA[row*ASTR + 512 + comp]         = hh;
      lA[ALIMB + row*ASTR + 512 + comp] = f2b(xv - b2f(hh));
    }
    __syncthreads();

    if (t > 0) phaseW(t-1, true);   // fills lA w-region; no second exchange

    // z = A @ Wc (20 kt, split hi/lo)
    f32x4 acc0 = {0.f,0.f,0.f,0.f}, acc1 = {0.f,0.f,0.f,0.f};
    const int arow = l15*ASTR + lhi*8;
    #pragma unroll
    for (int kt = 0; kt < 20; ++kt) {
      short8 ah = *(const short8*)&lA[arow + kt*32];
      short8 al = *(const short8*)&lA[ALIMB + arow + kt*32];
      acc0 = __builtin_amdgcn_mfma_f32_16x16x32_bf16(ah, bfh[kt], acc0, 0,0,0);
      acc1 = __builtin_amdgcn_mfma_f32_16x16x32_bf16(ah, bfl[kt], acc1, 0,0,0);
      acc1 = __builtin_amdgcn_mfma_f32_16x16x32_bf16(al, bfh[kt], acc1, 0,0,0);
    }

    // gates -> h_t
    #pragma unroll
    for (int r = 0; r < 4; ++r) {
      float v   = acc0[r] + acc1[r] + bias_r;
      float t4  = __shfl_xor(v, 4);
      float t8  = __shfl_xor(v, 8);
      float t12 = __shfl_xor(v, 12);
      float ig = sigm(v), fg = sigm(t4), gg = tanh_(t8), og = sigm(t12);
      float cn = fg*c_reg[r] + ig*gg;
      c_reg[r] = cn;
      float h = og*tanh_(cn);
      if (l15 < 4) {
        const int ui = wave*4 + l15;
        const int rr = lhi*4 + r;
        unsigned short h16 = f2b(h);
        lHout[rr*32 + ui]       = h16;
        lHout[512 + rr*32 + ui] = f2b(h - b2f(h16));
        out[((size_t)(g*16 + rr)*Tt + t)*512 + (jj*32 + ui)] = h;
      }
    }
    __syncthreads();

    // coalesced h stores + seq publish
    {
      unsigned short* hbn = hbG + ((t+1)&1)*HB_BUF;
      if (tid < 128) {
        const int rr = tid >> 3, limb = (tid >> 2) & 1, q = tid & 3;
        i32x4 v = *(const i32x4*)&lHout[limb*512 + rr*32 + q*8];
        gst16(hbn + limb*HB_LIMB + rr*512 + jj*32 + q*8, v);
        drain_vm();
      }
    }
    __syncthreads();
    if (tid == 0) gst4(seqG + jj, t+1);
  }

  // ---- epilogue: phi/w for t=799 ----
  if (wave == 0) {
    const int* sp = seqG + (lane & 15);
    int it = 0;
    for (;;) {
      int v = gld4(sp);
      if (__all(v >= Tt)) break;
      if (++it > POLL_CAP) break;
      __builtin_amdgcn_s_sleep(1);
    }
  }
  __syncthreads();
  {
    const unsigned short* hb = hbG + (Tt&1)*HB_BUF;   // h_799 in buf 0
    const int r0 = tid >> 6, q0 = lane;
    i32x4 va, vb, vc, vd;
    gld16(&va, hb + r0*512 + q0*8);
    gld16(&vb, hb + (r0+8)*512 + q0*8);
    gld16(&vc, hb + HB_LIMB + r0*512 + q0*8);
    gld16(&vd, hb + HB_LIMB + (r0+8)*512 + q0*8);
    WAIT_VM(0);
    __builtin_amdgcn_sched_barrier(0);
    *(i32x4*)&lA[r0*ASTR + q0*8]             = va;
    *(i32x4*)&lA[(r0+8)*ASTR + q0*8]         = vb;
    *(i32x4*)&lA[ALIMB + r0*ASTR + q0*8]     = vc;
    *(i32x4*)&lA[ALIMB + (r0+8)*ASTR + q0*8] = vd;
  }
  __syncthreads();
  phaseW(Tt-1, false);
}

extern "C" void kernel_launch(void* const* d_in, const int* in_sizes, int n_in,
                              void* d_out, int out_size, void* d_ws, size_t ws_size,
                              hipStream_t stream) {
  (void)in_sizes; (void)n_in; (void)out_size;
  if (ws_size < WS_NEED) return;
  const float* x    = (const float*)d_in[0];
  const float* sent = (const float*)d_in[1];
  const int*   sl   = (const int*)d_in[2];
  const float* Wx   = (const float*)d_in[3];
  const float* Wh   = (const float*)d_in[4];
  const float* bias = (const float*)d_in[5];
  const float* Wwin = (const float*)d_in[6];
  const float* bwin = (const float*)d_in[7];

  char* ws = (char*)d_ws;
  unsigned short* hbuf = (unsigned short*)(ws + WS_HBUF);
  int* seq = (int*)(ws + WS_SEQ);
  float* sentT = (float*)(ws + WS_SENTT);
  float* out = (float*)d_out;

  prep<<<3587, 256, 0, stream>>>(sent, hbuf, seq, sentT);
  rnn_main<<<NBLK, 512, 0, stream>>>(x, sl, bias, bwin, Wwin, Wx, Wh,
                                     hbuf, seq, sentT, out);
}